// Round 1
// baseline (125.858 us; speedup 1.0000x reference)
//
#include <hip/hip_runtime.h>
#include <math.h>

#define ORDER 32
#define TC 32

// h[b,t,d] = sum_{j=0}^{31} w[j] * x[b, t-31+j, d] + thr ; out = (h>=0) ? 1 : 0
// One thread per d (coalesced), TC time steps per thread with a 63-wide
// statically-indexed register window. f32 fast path + rare f64 recompute
// when |h| is within 1e-3 of the Heaviside boundary (zero-flip requirement).
__global__ __launch_bounds__(256)
void psn_kernel(const float* __restrict__ x,
                const float* __restrict__ w,
                const float* __restrict__ thr_p,
                float* __restrict__ out)
{
    const int T = 1024, D = 1024;
    const int d  = blockIdx.x * blockDim.x + threadIdx.x;   // 0..1023
    const int t0 = blockIdx.y * TC;
    const int b  = blockIdx.z;

    __shared__ float ws[ORDER];
    if (threadIdx.x < ORDER) ws[threadIdx.x] = w[threadIdx.x];
    __syncthreads();

    const float thr = thr_p[0];
    const size_t base = (size_t)b * T * D + d;
    const float* xb = x + base;
    float*       ob = out + base;

    // Register window: xv[i] = x[b, t0-31+i, d], i in [0, 63)
    float xv[TC + ORDER - 1];
    if (t0 != 0) {
        const float* p = xb + (size_t)(t0 - (ORDER - 1)) * D;
        #pragma unroll
        for (int i = 0; i < TC + ORDER - 1; ++i)
            xv[i] = p[(size_t)i * D];
    } else {
        #pragma unroll
        for (int i = 0; i < TC + ORDER - 1; ++i) {
            const int t = i - (ORDER - 1);
            xv[i] = (t >= 0) ? xb[(size_t)t * D] : 0.0f;
        }
    }

    float wr[ORDER];
    #pragma unroll
    for (int j = 0; j < ORDER; ++j) wr[j] = ws[j];

    #pragma unroll
    for (int tt = 0; tt < TC; ++tt) {
        float h = thr;
        #pragma unroll
        for (int j = 0; j < ORDER; ++j)
            h = fmaf(wr[j], xv[tt + j], h);

        float res;
        if (__builtin_expect(fabsf(h) < 1e-3f, 0)) {
            // Boundary case: recompute in f64 (products f32xf32 exact in f64).
            double hd = (double)thr;
            #pragma unroll
            for (int j = 0; j < ORDER; ++j)
                hd = fma((double)wr[j], (double)xv[tt + j], hd);
            res = (hd >= 0.0) ? 1.0f : 0.0f;
        } else {
            res = (h >= 0.0f) ? 1.0f : 0.0f;
        }
        ob[(size_t)(t0 + tt) * D] = res;
    }
}

extern "C" void kernel_launch(void* const* d_in, const int* in_sizes, int n_in,
                              void* d_out, int out_size, void* d_ws, size_t ws_size,
                              hipStream_t stream)
{
    const float* x   = (const float*)d_in[0];
    const float* w   = (const float*)d_in[1];   // 32 taps
    const float* thr = (const float*)d_in[2];   // scalar (-1)
    float* o = (float*)d_out;

    dim3 grid(1024 / 256, 1024 / TC, 16);       // (d-tiles, t-chunks, B)
    psn_kernel<<<grid, 256, 0, stream>>>(x, w, thr, o);
}